// Round 12
// baseline (206.190 us; speedup 1.0000x reference)
//
#include <hip/hip_runtime.h>

#define NB    4
#define NSEQ  1024
#define DMODEL 768
#define NH    12
#define DH    64

typedef __bf16 bf16x8 __attribute__((ext_vector_type(8)));
typedef float  floatx4 __attribute__((ext_vector_type(4)));
typedef unsigned int u32;

static __device__ __forceinline__ float bf2f(unsigned short u) {
    return __uint_as_float(((unsigned)u) << 16);
}
static __device__ __forceinline__ unsigned short f2bf(float f) {
    unsigned u = __float_as_uint(f);
    u += 0x7FFFu + ((u >> 16) & 1u);   // round-to-nearest-even
    return (unsigned short)(u >> 16);
}

// async global->LDS DMA, 16B per lane. LDS side must be (wave-uniform base +
// lane*16) — pass per-thread base + t*16 with contiguous lane order.
static __device__ __forceinline__ void gl_lds16(const void* g, void* l) {
    __builtin_amdgcn_global_load_lds(
        (const __attribute__((address_space(1))) unsigned int*)g,
        (__attribute__((address_space(3))) unsigned int*)l, 16, 0, 0);
}

// ---------------------------------------------------------------------------
// cast_x: x fp32 [4096*768] -> bf16
// ---------------------------------------------------------------------------
__global__ __launch_bounds__(256) void cast_x(
    const float* __restrict__ x, unsigned short* __restrict__ xb)
{
    const int g = blockIdx.x * 256 + threadIdx.x;
    const size_t base = (size_t)g * 8;
    float4 a = *(const float4*)(x + base);
    float4 b = *(const float4*)(x + base + 4);
    unsigned short o[8];
    o[0] = f2bf(a.x); o[1] = f2bf(a.y); o[2] = f2bf(a.z); o[3] = f2bf(a.w);
    o[4] = f2bf(b.x); o[5] = f2bf(b.y); o[6] = f2bf(b.z); o[7] = f2bf(b.w);
    *(uint4*)(xb + base) = *(uint4*)o;
}

// ---------------------------------------------------------------------------
// tr_w: W fp32 [768 k][768 c] -> Wt bf16 [768 c][768 k]  (z selects Wq/Wk/Wv)
// ---------------------------------------------------------------------------
__global__ __launch_bounds__(256) void tr_w(
    const float* __restrict__ Wq, const float* __restrict__ Wk,
    const float* __restrict__ Wv, unsigned short* __restrict__ Wt)
{
    const int z  = blockIdx.z;
    const float* __restrict__ W = (z == 0) ? Wq : (z == 1) ? Wk : Wv;
    const int c0 = blockIdx.x * 64;
    const int k0 = blockIdx.y * 64;
    const int t  = threadIdx.x;

    __shared__ float ls[64][65];

    const int lr = t >> 2;
    #pragma unroll
    for (int j = 0; j < 4; j++) {
        int col = (t & 3) * 16 + j * 4;
        float4 v = *(const float4*)(W + (size_t)(k0 + lr) * DMODEL + c0 + col);
        ls[lr][col + 0] = v.x; ls[lr][col + 1] = v.y;
        ls[lr][col + 2] = v.z; ls[lr][col + 3] = v.w;
    }
    __syncthreads();
    const int lc = t >> 2;
    #pragma unroll
    for (int j = 0; j < 4; j++) {
        int kb = (t & 3) * 16 + j * 4;
        ushort4 o;
        o.x = f2bf(ls[kb + 0][lc]); o.y = f2bf(ls[kb + 1][lc]);
        o.z = f2bf(ls[kb + 2][lc]); o.w = f2bf(ls[kb + 3][lc]);
        *(ushort4*)(Wt + (size_t)z * DMODEL * DMODEL + (size_t)(c0 + lc) * DMODEL + k0 + kb) = o;
    }
}

// ---------------------------------------------------------------------------
// qkv_mfma v4 (m97 structure): C[4096][768] = xb @ Wt[z]^T via MFMA bf16.
// 128x128 tile / block, BK=32, 4x global_load_lds width-16 staging per K-step.
// ---------------------------------------------------------------------------
__global__ __launch_bounds__(256) void qkv_mfma(
    const unsigned short* __restrict__ xb, const unsigned short* __restrict__ Wt,
    unsigned short* __restrict__ Q, unsigned short* __restrict__ K,
    unsigned short* __restrict__ V)
{
    const int z  = blockIdx.z;
    const int r0 = blockIdx.x * 128;
    const int c0 = blockIdx.y * 128;
    const int t    = threadIdx.x;
    const int wave = t >> 6, lane = t & 63;
    const int m = lane & 15, g = lane >> 4;

    const unsigned short* __restrict__ B = Wt + (size_t)z * DMODEL * DMODEL;

    __shared__ __align__(16) char sm[34816];
    unsigned short (*As)[32] = (unsigned short(*)[32])sm;            // 128x32
    unsigned short (*Bs)[32] = (unsigned short(*)[32])(sm + 8192);   // 128x32
    unsigned short (*Po)[136] = (unsigned short(*)[136])sm;          // epilogue

    const int wm = (wave >> 1) * 64;
    const int wn = (wave & 1) * 64;

    floatx4 acc[4][4] = {};

    const unsigned short* ga0 = xb + (size_t)(r0 + (t >> 2)) * DMODEL + (t & 3) * 8;
    const unsigned short* ga1 = ga0 + (size_t)64 * DMODEL;
    const unsigned short* gb0 = B  + (size_t)(c0 + (t >> 2)) * DMODEL + (t & 3) * 8;
    const unsigned short* gb1 = gb0 + (size_t)64 * DMODEL;
    unsigned short* la0 = (unsigned short*)sm + (size_t)t * 8;
    unsigned short* la1 = la0 + 2048;                        // rows 64..127
    unsigned short* lb0 = (unsigned short*)(sm + 8192) + (size_t)t * 8;
    unsigned short* lb1 = lb0 + 2048;

    for (int kk = 0; kk < DMODEL / 32; kk++) {
        gl_lds16(ga0 + kk * 32, la0);
        gl_lds16(ga1 + kk * 32, la1);
        gl_lds16(gb0 + kk * 32, lb0);
        gl_lds16(gb1 + kk * 32, lb1);
        __syncthreads();

        bf16x8 af[4], bf[4];
        #pragma unroll
        for (int mt = 0; mt < 4; mt++)
            af[mt] = *(const bf16x8*)&As[wm + mt * 16 + m][g * 8];
        #pragma unroll
        for (int nt = 0; nt < 4; nt++)
            bf[nt] = *(const bf16x8*)&Bs[wn + nt * 16 + m][g * 8];
        #pragma unroll
        for (int mt = 0; mt < 4; mt++)
            #pragma unroll
            for (int nt = 0; nt < 4; nt++)
                acc[mt][nt] = __builtin_amdgcn_mfma_f32_16x16x32_bf16(
                    af[mt], bf[nt], acc[mt][nt], 0, 0, 0);
        __syncthreads();
    }

    const float scale = (z == 0) ? 0.125f : 1.0f;
    #pragma unroll
    for (int mt = 0; mt < 4; mt++) {
        #pragma unroll
        for (int nt = 0; nt < 4; nt++) {
            int rloc = wm + mt * 16 + g * 4;
            int cloc = wn + nt * 16 + m;
            #pragma unroll
            for (int r = 0; r < 4; r++)
                Po[rloc + r][cloc] = f2bf(acc[mt][nt][r] * scale);
        }
    }
    __syncthreads();

    #pragma unroll
    for (int i = 0; i < 8; i++) {
        int ci = t + i * 256;                  // 0..2047 uint4 chunks
        int row = ci >> 4, off = (ci & 15) * 8;
        uint4 val = *(uint4*)&Po[row][off];
        if (z == 0) {
            *(uint4*)(Q + (size_t)(r0 + row) * DMODEL + c0 + off) = val;
        } else {
            unsigned short* Pp = (z == 1) ? K : V;
            int rr = r0 + row;
            int bb = rr >> 10, n = rr & 1023;
            int cc = c0 + off;
            int h = cc >> 6, d = cc & 63;
            *(uint4*)(Pp + (((size_t)bb * NH + h) * NSEQ + n) * DH + d) = val;
        }
    }
}

// ---------------------------------------------------------------------------
// score_gemm (r2 version): per (b,h): S = (Q_h/8).K_h^T via MFMA, 128x128.
// Writes P = exp(S) bf16 + partial per-q row sums to Lpart[bh][ktile][q].
// ---------------------------------------------------------------------------
__global__ __launch_bounds__(256) void score_gemm(
    const unsigned short* __restrict__ Q, const unsigned short* __restrict__ K,
    unsigned short* __restrict__ P, float* __restrict__ Lpart)
{
    const int bh = blockIdx.z;        // b*12+h
    const int b  = bh / NH, h = bh % NH;
    const int q0 = blockIdx.x * 128;
    const int k0 = blockIdx.y * 128;
    const int t    = threadIdx.x;
    const int wave = t >> 6, lane = t & 63;

    __shared__ __align__(16) char sm[36864];
    unsigned short (*Qs)[72] = (unsigned short(*)[72])sm;            // 128 x 72
    unsigned short (*Ks)[72] = (unsigned short(*)[72])(sm + 18432);  // 128 x 72
    unsigned short (*Po)[136] = (unsigned short(*)[136])sm;          // epilogue (34816 B)
    float (*rsum)[2] = (float(*)[2])(sm + 34816);                    // 128 x 2 (1 KB)

    #pragma unroll
    for (int i = 0; i < 4; i++) {
        int c = t + i * 256;              // 0..1023
        int row = c >> 3, off = (c & 7) * 8;
        uint4 qa = *(const uint4*)(Q + ((size_t)(b * NSEQ + q0 + row)) * DMODEL + h * DH + off);
        uint4 ka = *(const uint4*)(K + (((size_t)bh) * NSEQ + (k0 + row)) * DH + off);
        *(uint4*)&Qs[row][off] = qa;
        *(uint4*)&Ks[row][off] = ka;
    }
    __syncthreads();

    const int wq = (wave >> 1) * 64, wk2 = (wave & 1) * 64;
    const int m = lane & 15, g = lane >> 4;

    floatx4 acc[4][4] = {};
    #pragma unroll
    for (int ds = 0; ds < 2; ds++) {
        const int dd = ds * 32 + g * 8;
        bf16x8 af[4], bf[4];
        #pragma unroll
        for (int mt = 0; mt < 4; mt++)
            af[mt] = *(const bf16x8*)&Qs[wq + mt * 16 + m][dd];
        #pragma unroll
        for (int nt = 0; nt < 4; nt++)
            bf[nt] = *(const bf16x8*)&Ks[wk2 + nt * 16 + m][dd];
        #pragma unroll
        for (int mt = 0; mt < 4; mt++)
            #pragma unroll
            for (int nt = 0; nt < 4; nt++)
                acc[mt][nt] = __builtin_amdgcn_mfma_f32_16x16x32_bf16(
                    af[mt], bf[nt], acc[mt][nt], 0, 0, 0);
    }

    __syncthreads();
    float rs[4][4] = {};
    #pragma unroll
    for (int mt = 0; mt < 4; mt++) {
        #pragma unroll
        for (int nt = 0; nt < 4; nt++) {
            int qloc = wq + mt * 16 + g * 4;
            int kloc = wk2 + nt * 16 + m;
            #pragma unroll
            for (int r = 0; r < 4; r++) {
                float e = __expf(acc[mt][nt][r]);
                Po[qloc + r][kloc] = f2bf(e);
                rs[mt][r] += e;
            }
        }
    }
    #pragma unroll
    for (int mt = 0; mt < 4; mt++)
        #pragma unroll
        for (int r = 0; r < 4; r++) {
            float x = rs[mt][r];
            #pragma unroll
            for (int off = 1; off < 16; off <<= 1)
                x += __shfl_xor(x, off, 64);
            rs[mt][r] = x;
        }
    if (m == 0) {
        #pragma unroll
        for (int mt = 0; mt < 4; mt++)
            #pragma unroll
            for (int r = 0; r < 4; r++)
                rsum[wq + mt * 16 + g * 4 + r][wk2 >> 6] = rs[mt][r];
    }
    __syncthreads();

    if (t < 128)
        Lpart[((size_t)bh * 8 + blockIdx.y) * NSEQ + q0 + t] = rsum[t][0] + rsum[t][1];

    #pragma unroll
    for (int i = 0; i < 8; i++) {
        int c = t + i * 256;              // 0..2047
        int row = c >> 4, off = (c & 15) * 8;
        *(uint4*)(P + (((size_t)bh * NSEQ) + q0 + row) * NSEQ + k0 + off) =
            *(uint4*)&Po[row][off];
    }
}

// ---------------------------------------------------------------------------
// mix_t v9: v8 (DMA staging, 43.5us) + __launch_bounds__(256, 8) to force
// allocated VGPR <= 64 (the m69 occupancy granule). v8's live set (p[48] +
// ~12 scalars; praw gone via DMA, rs gone via inline reduce) should fit 64.
// Static residency cap then moves 16 -> 24 waves/CU (LDS-bound at 25.6KB).
// ---------------------------------------------------------------------------
__global__ __launch_bounds__(256, 8) void mix_t(
    unsigned short* __restrict__ P, const float* __restrict__ theta,
    const float* __restrict__ Lpart, float* __restrict__ Rbuf)
{
    const int t = threadIdx.x;
    const int wave = t >> 6, lane = t & 63;
    const int q = blockIdx.x, b = blockIdx.y;

    __shared__ __align__(16) unsigned short Ps[12][1024];  // 24576 B
    __shared__ float th_s[144];      // theta[h][i] / l_h (block-uniform)
    __shared__ float red[4][12];

    unsigned short* Pq = P + ((size_t)b * NH * NSEQ + q) * NSEQ;

    // async-DMA all 12 P planes into LDS: slot = j*256+t covers plane
    // h = slot/128, elements [(slot%128)*8 .. +8). LDS byte = slot*16 is
    // linear in t (wave-uniform base + lane*16) as gl_lds16 requires.
    #pragma unroll
    for (int j = 0; j < 6; j++) {
        int slot = j * 256 + t;          // 0..1535
        int h = slot >> 7;
        int ke = (slot & 127) * 8;
        gl_lds16(Pq + (size_t)h * NSEQ * NSEQ + ke, (char*)Ps + (size_t)slot * 16);
    }

    // denominators: lanes 0..11 of every wave (redundant, barrier-free)
    float rl = 0.f;
    if (lane < 12) {
        float s = 0.f;
        #pragma unroll
        for (int kt = 0; kt < 8; kt++)
            s += Lpart[(((size_t)(b * NH + lane)) * 8 + kt) * NSEQ + q];
        rl = 1.0f / s;
    }
    if (t < 144) {
        float rlq = __shfl(rl, t / 12, 64);   // lane t/12 of caller's own wave
        th_s[t] = theta[t] * rlq;
    }
    __syncthreads();   // DMA drained (vmcnt 0 before barrier) + th_s ready

    // unpack LDS -> p[12][4]; thread t owns k in [t*4, t*4+4)
    float p[12][4];
    #pragma unroll
    for (int h = 0; h < 12; h++) {
        uint2 w2 = *(const uint2*)&Ps[h][t * 4];
        p[h][0] = __uint_as_float(w2.x << 16);
        p[h][1] = __uint_as_float(w2.x & 0xffff0000u);
        p[h][2] = __uint_as_float(w2.y << 16);
        p[h][3] = __uint_as_float(w2.y & 0xffff0000u);
    }

    // mix + store + INLINE per-i wave reduce (keeps live set ~ p[48] + few)
    float myrs = 0.f;
    #pragma unroll
    for (int i = 0; i < 12; i++) {
        float s0 = 0.f, s1 = 0.f, s2 = 0.f, s3 = 0.f;
        #pragma unroll
        for (int h = 0; h < 12; h++) {
            float th = th_s[h * 12 + i];
            s0 = fmaf(th, p[h][0], s0); s1 = fmaf(th, p[h][1], s1);
            s2 = fmaf(th, p[h][2], s2); s3 = fmaf(th, p[h][3], s3);
        }
        ushort4 o;
        o.x = f2bf(s0); o.y = f2bf(s1); o.z = f2bf(s2); o.w = f2bf(s3);
        *(ushort4*)(Pq + (size_t)i * NSEQ * NSEQ + t * 4) = o;
        float x = fmaf(s0, s0, fmaf(s1, s1, fmaf(s2, s2, s3 * s3)));
        #pragma unroll
        for (int off = 32; off > 0; off >>= 1)
            x += __shfl_xor(x, off, 64);
        if (lane == i) myrs = x;
    }
    if (lane < 12) red[wave][lane] = myrs;
    __syncthreads();

    if (t < 12) {
        float sum2 = red[0][t] + red[1][t] + red[2][t] + red[3][t];
        float mean = 0.f;
        #pragma unroll
        for (int h = 0; h < 12; h++) mean += theta[h * 12 + t];  // unscaled
        mean *= (1.0f / 1024.0f);
        float var = sum2 * (1.0f / 1024.0f) - mean * mean;
        Rbuf[(size_t)(b * NH + t) * NSEQ + q] = rsqrtf(var + 1e-6f);
    }
}

// ---------------------------------------------------------------------------
// av_mfma v6 (r8/r10 version): out = lns_k*(M[k,d] - mean_i*C1[d]) + lnb_k*C2[d]
//   M = MFMA(T^T, rstd_q*V);  C1 = sum_q rstd_q*V;  C2 = sum_q V.
// Vt pack via native __bf16 pair casts (v_cvt_pk_bf16_f32).
// ---------------------------------------------------------------------------
__global__ __launch_bounds__(256) void av_mfma(
    const unsigned short* __restrict__ A, const unsigned short* __restrict__ V,
    const float* __restrict__ Rbuf, const float* __restrict__ theta,
    const float* __restrict__ ln_scale, const float* __restrict__ ln_bias,
    float* __restrict__ out)
{
    const int b  = blockIdx.z;
    const int i  = blockIdx.y;
    const int k0 = blockIdx.x * 64;
    const int t  = threadIdx.x;
    const int wave = t >> 6, lane = t & 63;
    const int m = lane & 15, g = lane >> 4;

    __shared__ __align__(16) u32 At[64 * 33 + 64];   // pack area; reused for C1 reduce
    __shared__ __align__(16) u32 Vt[64 * 33 + 64];   // pack area; reused for C2 reduce

    const unsigned short* Ai = A + ((size_t)(b * NH + i)) * NSEQ * NSEQ;
    const unsigned short* Vi = V + ((size_t)(b * NH + i)) * NSEQ * DH;
    const float* Rb = Rbuf + (size_t)(b * NH + i) * NSEQ;

    const int wk = (wave >> 1) * 32;
    const int wd = (wave & 1) * 32;

    floatx4 acc[2][2] = {};
    float c1[4] = {}, c2[4] = {};
    const int k4s = (t & 15) * 4;       // this thread's d-range (same for both l)

    for (int q0 = 0; q0 < NSEQ; q0 += 64) {
        ushort4 a0[2], a1[2], v0[2], v1[2];
        float2 rr[2];
        #pragma unroll
        for (int l = 0; l < 2; l++) {
            int c = t + l * 256;          // 0..511
            int k4 = (c & 15) * 4;
            int qp = c >> 4;
            a0[l] = *(const ushort4*)(Ai + (size_t)(q0 + 2 * qp)     * NSEQ + k0 + k4);
            a1[l] = *(const ushort4*)(Ai + (size_t)(q0 + 2 * qp + 1) * NSEQ + k0 + k4);
            v0[l] = *(const ushort4*)(Vi + (size_t)(q0 + 2 * qp)     * DH + k4);
            v1[l] = *(const ushort4*)(Vi + (size_t)(q0 + 2 * qp + 1) * DH + k4);
            rr[l] = *(const float2*)(Rb + q0 + 2 * qp);
        }
        __syncthreads();
        #pragma unroll
        for (int l = 0; l < 2; l++) {
            int c = t + l * 256;
            int k4 = (c & 15) * 4;
            int qp = c >> 4;
            const unsigned short* pa0 = (const unsigned short*)&a0[l];
            const unsigned short* pa1 = (const unsigned short*)&a1[l];
            const unsigned short* pv0 = (const unsigned short*)&v0[l];
            const unsigned short* pv1 = (const unsigned short*)&v1[l];
            #pragma unroll
            for (int j = 0; j < 4; j++) {
                At[(k4 + j) * 33 + qp] = (u32)pa0[j] | ((u32)pa1[j] << 16);
                float vf0 = bf2f(pv0[j]), vf1 = bf2f(pv1[j]);
                float s0 = rr[l].x * vf0, s1 = rr[l].y * vf1;
                u32 w;
                __bf16* wb = (__bf16*)&w;
                wb[0] = (__bf16)s0;       // compiler: v_cvt_pk_bf16_f32
                wb[1] = (__bf16)s1;
                Vt[(k4 + j) * 33 + qp] = w;
                c1[j] += s0 + s1;
                c2[j] += vf0 + vf1;
            }
        }
        __syncthreads();

        #pragma unroll
        for (int ks = 0; ks < 2; ks++) {
            const int qo = ks * 16 + g * 4;
            bf16x8 af[2], bf[2];
            #pragma unroll
            for (int mt = 0; mt < 2; mt++) {
                const u32* r = &At[(wk + mt * 16 + m) * 33 + qo];
                uint4 w; w.x = r[0]; w.y = r[1]; w.z = r[2]; w.w = r[3];
                af[mt] = *(bf16x8*)&w;
            }
            #pragma unroll
            for (int nt = 0; nt < 2; nt++) {
                const u32* r = &Vt[(wd + nt * 16 + m) * 33 + qo];
                uint4 w; w.x = r[0]; w.y = r[1]; w.z = r[2]; w.w = r[3];
                bf[nt] = *(bf16x8*)&w;
            }
            #pragma unroll
            for (int mt = 0; mt < 2; mt++)
                #pragma unroll
                for (int nt = 0; nt < 2; nt++)
                    acc[mt][nt] = __builtin_amdgcn_mfma_f32_16x16x32_bf16(
                        af[mt], bf[nt], acc[mt][nt], 0, 0, 0);
        }
    }

    // ---- reduce C1/C2 across the 16 qp-groups (reuse At/Vt as float arrays)
    __syncthreads();
    float* c1l = (float*)At;              // [16][64] partials + [64] final at 1024
    float* c2l = (float*)Vt;
    const int grp = t >> 4;
    #pragma unroll
    for (int j = 0; j < 4; j++) {
        c1l[grp * 64 + k4s + j] = c1[j];
        c2l[grp * 64 + k4s + j] = c2[j];
    }
    __syncthreads();
    if (t < 64) {
        float s1_ = 0.f, s2_ = 0.f;
        #pragma unroll
        for (int g2 = 0; g2 < 16; g2++) {
            s1_ += c1l[g2 * 64 + t];
            s2_ += c2l[g2 * 64 + t];
        }
        c1l[1024 + t] = s1_;
        c2l[1024 + t] = s2_;
    }
    __syncthreads();

    float mean = 0.f;
    #pragma unroll
    for (int h = 0; h < 12; h++) mean += theta[h * 12 + i];
    mean *= (1.0f / 1024.0f);

    #pragma unroll
    for (int mt = 0; mt < 2; mt++) {
        int kb = k0 + wk + mt * 16 + g * 4;
        float4 ls4 = *(const float4*)(ln_scale + kb);
        float4 lb4 = *(const float4*)(ln_bias + kb);
        #pragma unroll
        for (int nt = 0; nt < 2; nt++) {
            int d = wd + nt * 16 + m;
            float C1d = c1l[1024 + d], C2d = c2l[1024 + d];
            #pragma unroll
            for (int r = 0; r < 4; r++) {
                float lns = (&ls4.x)[r], lnb = (&lb4.x)[r];
                float val = lns * (acc[mt][nt][r] - mean * C1d) + lnb * C2d;
                out[((size_t)(b * NSEQ + kb + r)) * DMODEL + i * DH + d] = val;
            }
        }
    }
}

extern "C" void kernel_launch(void* const* d_in, const int* in_sizes, int n_in,
                              void* d_out, int out_size, void* d_ws, size_t ws_size,
                              hipStream_t stream) {
    const float* x     = (const float*)d_in[0];
    const float* Wq    = (const float*)d_in[1];
    const float* Wk    = (const float*)d_in[2];
    const float* Wv    = (const float*)d_in[3];
    const float* theta = (const float*)d_in[4];
    const float* ln_s  = (const float*)d_in[5];
    const float* ln_b  = (const float*)d_in[6];
    float* out = (float*)d_out;

    char* ws = (char*)d_ws;
    const size_t qsz = (size_t)NB * NSEQ * DMODEL * sizeof(unsigned short); // 6.29 MB
    unsigned short* Q = (unsigned short*)(ws);
    unsigned short* K = (unsigned short*)(ws + qsz);
    unsigned short* V = (unsigned short*)(ws + 2 * qsz);
    unsigned short* P = (unsigned short*)(ws + 3 * qsz);  // 100.7 MB, becomes T in-place
    unsigned short* xb = P;
    unsigned short* Wt = P + (size_t)NB * NSEQ * DMODEL;  // 3 x 768 x 768 bf16

    float* Lpart = out;                      // [48 * 8 * 1024 floats]
    float* Rbuf  = (float*)K;                // [48 * 1024 floats] (K dead after score)

    cast_x<<<dim3(NB * NSEQ * DMODEL / 2048), 256, 0, stream>>>(x, xb);
    tr_w<<<dim3(12, 12, 3), 256, 0, stream>>>(Wq, Wk, Wv, Wt);
    qkv_mfma<<<dim3(NB * NSEQ / 128, DMODEL / 128, 3), 256, 0, stream>>>(
        xb, Wt, Q, K, V);
    score_gemm<<<dim3(NSEQ / 128, NSEQ / 128, NB * NH), 256, 0, stream>>>(Q, K, P, Lpart);
    mix_t<<<dim3(NSEQ, NB), 256, 0, stream>>>(P, theta, Lpart, Rbuf);
    av_mfma<<<dim3(NSEQ / 64, NH, NB), 256, 0, stream>>>(
        P, V, Rbuf, theta, ln_s, ln_b, out);
}

// Round 14
// 204.766 us; speedup vs baseline: 1.0070x; 1.0070x over previous
//
#include <hip/hip_runtime.h>

#define NB    4
#define NSEQ  1024
#define DMODEL 768
#define NH    12
#define DH    64

typedef __bf16 bf16x8 __attribute__((ext_vector_type(8)));
typedef float  floatx4 __attribute__((ext_vector_type(4)));
typedef unsigned int u32;

static __device__ __forceinline__ float bf2f(unsigned short u) {
    return __uint_as_float(((unsigned)u) << 16);
}
static __device__ __forceinline__ unsigned short f2bf(float f) {
    unsigned u = __float_as_uint(f);
    u += 0x7FFFu + ((u >> 16) & 1u);   // round-to-nearest-even
    return (unsigned short)(u >> 16);
}

// async global->LDS DMA, 16B per lane. LDS side must be (wave-uniform base +
// lane*16) — pass per-thread base + t*16 with contiguous lane order.
static __device__ __forceinline__ void gl_lds16(const void* g, void* l) {
    __builtin_amdgcn_global_load_lds(
        (const __attribute__((address_space(1))) unsigned int*)g,
        (__attribute__((address_space(3))) unsigned int*)l, 16, 0, 0);
}

// ---------------------------------------------------------------------------
// prep: merged cast_x + tr_w (one launch instead of two).
// blocks [0, 1536): x fp32 [4096*768] -> xb bf16   (1536*256*8 = 3.15M elems)
// blocks [1536, 1968): W fp32 [768][768] -> Wt bf16 transposed (z = Wq/Wk/Wv)
// ---------------------------------------------------------------------------
__global__ __launch_bounds__(256) void prep(
    const float* __restrict__ x, unsigned short* __restrict__ xb,
    const float* __restrict__ Wq, const float* __restrict__ Wk,
    const float* __restrict__ Wv, unsigned short* __restrict__ Wt)
{
    const int t = threadIdx.x;
    if (blockIdx.x < 1536) {
        const int g = blockIdx.x * 256 + t;
        const size_t base = (size_t)g * 8;
        float4 a = *(const float4*)(x + base);
        float4 b = *(const float4*)(x + base + 4);
        unsigned short o[8];
        o[0] = f2bf(a.x); o[1] = f2bf(a.y); o[2] = f2bf(a.z); o[3] = f2bf(a.w);
        o[4] = f2bf(b.x); o[5] = f2bf(b.y); o[6] = f2bf(b.z); o[7] = f2bf(b.w);
        *(uint4*)(xb + base) = *(uint4*)o;
        return;
    }
    const int rid = blockIdx.x - 1536;       // 0..431
    const int z   = rid / 144;
    const int rem = rid % 144;
    const int c0  = (rem % 12) * 64;
    const int k0  = (rem / 12) * 64;
    const float* __restrict__ W = (z == 0) ? Wq : (z == 1) ? Wk : Wv;

    __shared__ float ls[64][65];

    const int lr = t >> 2;
    #pragma unroll
    for (int j = 0; j < 4; j++) {
        int col = (t & 3) * 16 + j * 4;
        float4 v = *(const float4*)(W + (size_t)(k0 + lr) * DMODEL + c0 + col);
        ls[lr][col + 0] = v.x; ls[lr][col + 1] = v.y;
        ls[lr][col + 2] = v.z; ls[lr][col + 3] = v.w;
    }
    __syncthreads();
    const int lc = t >> 2;
    #pragma unroll
    for (int j = 0; j < 4; j++) {
        int kb = (t & 3) * 16 + j * 4;
        ushort4 o;
        o.x = f2bf(ls[kb + 0][lc]); o.y = f2bf(ls[kb + 1][lc]);
        o.z = f2bf(ls[kb + 2][lc]); o.w = f2bf(ls[kb + 3][lc]);
        *(ushort4*)(Wt + (size_t)z * DMODEL * DMODEL + (size_t)(c0 + lc) * DMODEL + k0 + kb) = o;
    }
}

// ---------------------------------------------------------------------------
// qkv_mfma v5: m97 structure + T1 XCD swizzle over the 192-tile (x,y) space
// (192 % 8 == 0 -> bijective). Each XCD gets a contiguous 24-tile chunk ->
// neighboring C-tiles (sharing Wt/xb panels) land in the same L2.
// ---------------------------------------------------------------------------
__global__ __launch_bounds__(256) void qkv_mfma(
    const unsigned short* __restrict__ xb, const unsigned short* __restrict__ Wt,
    unsigned short* __restrict__ Q, unsigned short* __restrict__ K,
    unsigned short* __restrict__ V)
{
    const int z  = blockIdx.z;
    const int o  = blockIdx.x + blockIdx.y * 32;      // 0..191
    const int w  = (o & 7) * 24 + (o >> 3);           // XCD-chunked
    const int r0 = (w % 32) * 128;
    const int c0 = (w / 32) * 128;
    const int t    = threadIdx.x;
    const int wave = t >> 6, lane = t & 63;
    const int m = lane & 15, g = lane >> 4;

    const unsigned short* __restrict__ B = Wt + (size_t)z * DMODEL * DMODEL;

    __shared__ __align__(16) char sm[34816];
    unsigned short (*As)[32] = (unsigned short(*)[32])sm;            // 128x32
    unsigned short (*Bs)[32] = (unsigned short(*)[32])(sm + 8192);   // 128x32
    unsigned short (*Po)[136] = (unsigned short(*)[136])sm;          // epilogue

    const int wm = (wave >> 1) * 64;
    const int wn = (wave & 1) * 64;

    floatx4 acc[4][4] = {};

    const unsigned short* ga0 = xb + (size_t)(r0 + (t >> 2)) * DMODEL + (t & 3) * 8;
    const unsigned short* ga1 = ga0 + (size_t)64 * DMODEL;
    const unsigned short* gb0 = B  + (size_t)(c0 + (t >> 2)) * DMODEL + (t & 3) * 8;
    const unsigned short* gb1 = gb0 + (size_t)64 * DMODEL;
    unsigned short* la0 = (unsigned short*)sm + (size_t)t * 8;
    unsigned short* la1 = la0 + 2048;                        // rows 64..127
    unsigned short* lb0 = (unsigned short*)(sm + 8192) + (size_t)t * 8;
    unsigned short* lb1 = lb0 + 2048;

    for (int kk = 0; kk < DMODEL / 32; kk++) {
        gl_lds16(ga0 + kk * 32, la0);
        gl_lds16(ga1 + kk * 32, la1);
        gl_lds16(gb0 + kk * 32, lb0);
        gl_lds16(gb1 + kk * 32, lb1);
        __syncthreads();

        bf16x8 af[4], bf[4];
        #pragma unroll
        for (int mt = 0; mt < 4; mt++)
            af[mt] = *(const bf16x8*)&As[wm + mt * 16 + m][g * 8];
        #pragma unroll
        for (int nt = 0; nt < 4; nt++)
            bf[nt] = *(const bf16x8*)&Bs[wn + nt * 16 + m][g * 8];
        #pragma unroll
        for (int mt = 0; mt < 4; mt++)
            #pragma unroll
            for (int nt = 0; nt < 4; nt++)
                acc[mt][nt] = __builtin_amdgcn_mfma_f32_16x16x32_bf16(
                    af[mt], bf[nt], acc[mt][nt], 0, 0, 0);
        __syncthreads();
    }

    const float scale = (z == 0) ? 0.125f : 1.0f;
    #pragma unroll
    for (int mt = 0; mt < 4; mt++) {
        #pragma unroll
        for (int nt = 0; nt < 4; nt++) {
            int rloc = wm + mt * 16 + g * 4;
            int cloc = wn + nt * 16 + m;
            #pragma unroll
            for (int r = 0; r < 4; r++)
                Po[rloc + r][cloc] = f2bf(acc[mt][nt][r] * scale);
        }
    }
    __syncthreads();

    #pragma unroll
    for (int i = 0; i < 8; i++) {
        int ci = t + i * 256;                  // 0..2047 uint4 chunks
        int row = ci >> 4, off = (ci & 15) * 8;
        uint4 val = *(uint4*)&Po[row][off];
        if (z == 0) {
            *(uint4*)(Q + (size_t)(r0 + row) * DMODEL + c0 + off) = val;
        } else {
            unsigned short* Pp = (z == 1) ? K : V;
            int rr = r0 + row;
            int bb = rr >> 10, n = rr & 1023;
            int cc = c0 + off;
            int h = cc >> 6, d = cc & 63;
            *(uint4*)(Pp + (((size_t)bb * NH + h) * NSEQ + n) * DH + d) = val;
        }
    }
}

// ---------------------------------------------------------------------------
// score_gemm v3: r2 structure + T1 XCD swizzle over the 64-tile (q,k) space
// per bh (64 % 8 == 0 -> bijective). Each XCD gets one fixed k-tile (shares
// the 16KB K panel in its L2) and streams all 8 q-tiles.
// ---------------------------------------------------------------------------
__global__ __launch_bounds__(256) void score_gemm(
    const unsigned short* __restrict__ Q, const unsigned short* __restrict__ K,
    unsigned short* __restrict__ P, float* __restrict__ Lpart)
{
    const int bh = blockIdx.z;        // b*12+h
    const int b  = bh / NH, h = bh % NH;
    const int o  = blockIdx.x + blockIdx.y * 8;   // 0..63
    const int w  = (o & 7) * 8 + (o >> 3);        // XCD-chunked
    const int qx = w & 7, ky = w >> 3;
    const int q0 = qx * 128;
    const int k0 = ky * 128;
    const int t    = threadIdx.x;
    const int wave = t >> 6, lane = t & 63;

    __shared__ __align__(16) char sm[36864];
    unsigned short (*Qs)[72] = (unsigned short(*)[72])sm;            // 128 x 72
    unsigned short (*Ks)[72] = (unsigned short(*)[72])(sm + 18432);  // 128 x 72
    unsigned short (*Po)[136] = (unsigned short(*)[136])sm;          // epilogue (34816 B)
    float (*rsum)[2] = (float(*)[2])(sm + 34816);                    // 128 x 2 (1 KB)

    #pragma unroll
    for (int i = 0; i < 4; i++) {
        int c = t + i * 256;              // 0..1023
        int row = c >> 3, off = (c & 7) * 8;
        uint4 qa = *(const uint4*)(Q + ((size_t)(b * NSEQ + q0 + row)) * DMODEL + h * DH + off);
        uint4 ka = *(const uint4*)(K + (((size_t)bh) * NSEQ + (k0 + row)) * DH + off);
        *(uint4*)&Qs[row][off] = qa;
        *(uint4*)&Ks[row][off] = ka;
    }
    __syncthreads();

    const int wq = (wave >> 1) * 64, wk2 = (wave & 1) * 64;
    const int m = lane & 15, g = lane >> 4;

    floatx4 acc[4][4] = {};
    #pragma unroll
    for (int ds = 0; ds < 2; ds++) {
        const int dd = ds * 32 + g * 8;
        bf16x8 af[4], bf[4];
        #pragma unroll
        for (int mt = 0; mt < 4; mt++)
            af[mt] = *(const bf16x8*)&Qs[wq + mt * 16 + m][dd];
        #pragma unroll
        for (int nt = 0; nt < 4; nt++)
            bf[nt] = *(const bf16x8*)&Ks[wk2 + nt * 16 + m][dd];
        #pragma unroll
        for (int mt = 0; mt < 4; mt++)
            #pragma unroll
            for (int nt = 0; nt < 4; nt++)
                acc[mt][nt] = __builtin_amdgcn_mfma_f32_16x16x32_bf16(
                    af[mt], bf[nt], acc[mt][nt], 0, 0, 0);
    }

    __syncthreads();
    float rs[4][4] = {};
    #pragma unroll
    for (int mt = 0; mt < 4; mt++) {
        #pragma unroll
        for (int nt = 0; nt < 4; nt++) {
            int qloc = wq + mt * 16 + g * 4;
            int kloc = wk2 + nt * 16 + m;
            #pragma unroll
            for (int r = 0; r < 4; r++) {
                float e = __expf(acc[mt][nt][r]);
                Po[qloc + r][kloc] = f2bf(e);
                rs[mt][r] += e;
            }
        }
    }
    #pragma unroll
    for (int mt = 0; mt < 4; mt++)
        #pragma unroll
        for (int r = 0; r < 4; r++) {
            float x = rs[mt][r];
            #pragma unroll
            for (int off = 1; off < 16; off <<= 1)
                x += __shfl_xor(x, off, 64);
            rs[mt][r] = x;
        }
    if (m == 0) {
        #pragma unroll
        for (int mt = 0; mt < 4; mt++)
            #pragma unroll
            for (int r = 0; r < 4; r++)
                rsum[wq + mt * 16 + g * 4 + r][wk2 >> 6] = rs[mt][r];
    }
    __syncthreads();

    if (t < 128)
        Lpart[((size_t)bh * 8 + ky) * NSEQ + q0 + t] = rsum[t][0] + rsum[t][1];

    #pragma unroll
    for (int i = 0; i < 8; i++) {
        int c = t + i * 256;              // 0..2047
        int row = c >> 4, off = (c & 15) * 8;
        *(uint4*)(P + (((size_t)bh * NSEQ) + q0 + row) * NSEQ + k0 + off) =
            *(uint4*)&Po[row][off];
    }
}

// ---------------------------------------------------------------------------
// mix_t v8 (r11 exact, 43.5us best): block-per-(b,q); P planes via
// global_load_lds DMA (24KB LDS), theta/l fold, inline per-i shfl reduce.
// ---------------------------------------------------------------------------
__global__ __launch_bounds__(256) void mix_t(
    unsigned short* __restrict__ P, const float* __restrict__ theta,
    const float* __restrict__ Lpart, float* __restrict__ Rbuf)
{
    const int t = threadIdx.x;
    const int wave = t >> 6, lane = t & 63;
    const int q = blockIdx.x, b = blockIdx.y;

    __shared__ __align__(16) unsigned short Ps[12][1024];  // 24576 B
    __shared__ float th_s[144];      // theta[h][i] / l_h (block-uniform)
    __shared__ float red[4][12];

    unsigned short* Pq = P + ((size_t)b * NH * NSEQ + q) * NSEQ;

    #pragma unroll
    for (int j = 0; j < 6; j++) {
        int slot = j * 256 + t;          // 0..1535
        int h = slot >> 7;
        int ke = (slot & 127) * 8;
        gl_lds16(Pq + (size_t)h * NSEQ * NSEQ + ke, (char*)Ps + (size_t)slot * 16);
    }

    float rl = 0.f;
    if (lane < 12) {
        float s = 0.f;
        #pragma unroll
        for (int kt = 0; kt < 8; kt++)
            s += Lpart[(((size_t)(b * NH + lane)) * 8 + kt) * NSEQ + q];
        rl = 1.0f / s;
    }
    if (t < 144) {
        float rlq = __shfl(rl, t / 12, 64);   // lane t/12 of caller's own wave
        th_s[t] = theta[t] * rlq;
    }
    __syncthreads();   // DMA drained + th_s ready

    float p[12][4];
    #pragma unroll
    for (int h = 0; h < 12; h++) {
        uint2 w2 = *(const uint2*)&Ps[h][t * 4];
        p[h][0] = __uint_as_float(w2.x << 16);
        p[h][1] = __uint_as_float(w2.x & 0xffff0000u);
        p[h][2] = __uint_as_float(w2.y << 16);
        p[h][3] = __uint_as_float(w2.y & 0xffff0000u);
    }

    float myrs = 0.f;
    #pragma unroll
    for (int i = 0; i < 12; i++) {
        float s0 = 0.f, s1 = 0.f, s2 = 0.f, s3 = 0.f;
        #pragma unroll
        for (int h = 0; h < 12; h++) {
            float th = th_s[h * 12 + i];
            s0 = fmaf(th, p[h][0], s0); s1 = fmaf(th, p[h][1], s1);
            s2 = fmaf(th, p[h][2], s2); s3 = fmaf(th, p[h][3], s3);
        }
        ushort4 o;
        o.x = f2bf(s0); o.y = f2bf(s1); o.z = f2bf(s2); o.w = f2bf(s3);
        *(ushort4*)(Pq + (size_t)i * NSEQ * NSEQ + t * 4) = o;
        float x = fmaf(s0, s0, fmaf(s1, s1, fmaf(s2, s2, s3 * s3)));
        #pragma unroll
        for (int off = 32; off > 0; off >>= 1)
            x += __shfl_xor(x, off, 64);
        if (lane == i) myrs = x;
    }
    if (lane < 12) red[wave][lane] = myrs;
    __syncthreads();

    if (t < 12) {
        float sum2 = red[0][t] + red[1][t] + red[2][t] + red[3][t];
        float mean = 0.f;
        #pragma unroll
        for (int h = 0; h < 12; h++) mean += theta[h * 12 + t];  // unscaled
        mean *= (1.0f / 1024.0f);
        float var = sum2 * (1.0f / 1024.0f) - mean * mean;
        Rbuf[(size_t)(b * NH + t) * NSEQ + q] = rsqrtf(var + 1e-6f);
    }
}

// ---------------------------------------------------------------------------
// av_mfma v7: r8 structure + T1 XCD swizzle over the 16 k-tiles (16 % 8 == 0
// -> bijective; each XCD gets 2 adjacent k-tiles, shares Vi/Rb in its L2).
//   out = lns_k*(M[k,d] - mean_i*C1[d]) + lnb_k*C2[d]
//   M = MFMA(T^T, rstd_q*V);  C1 = sum_q rstd_q*V;  C2 = sum_q V.
// ---------------------------------------------------------------------------
__global__ __launch_bounds__(256) void av_mfma(
    const unsigned short* __restrict__ A, const unsigned short* __restrict__ V,
    const float* __restrict__ Rbuf, const float* __restrict__ theta,
    const float* __restrict__ ln_scale, const float* __restrict__ ln_bias,
    float* __restrict__ out)
{
    const int b  = blockIdx.z;
    const int i  = blockIdx.y;
    const int kx = (blockIdx.x & 7) * 2 + (blockIdx.x >> 3);   // XCD-chunked
    const int k0 = kx * 64;
    const int t  = threadIdx.x;
    const int wave = t >> 6, lane = t & 63;
    const int m = lane & 15, g = lane >> 4;

    __shared__ __align__(16) u32 At[64 * 33 + 64];   // pack area; reused for C1 reduce
    __shared__ __align__(16) u32 Vt[64 * 33 + 64];   // pack area; reused for C2 reduce

    const unsigned short* Ai = A + ((size_t)(b * NH + i)) * NSEQ * NSEQ;
    const unsigned short* Vi = V + ((size_t)(b * NH + i)) * NSEQ * DH;
    const float* Rb = Rbuf + (size_t)(b * NH + i) * NSEQ;

    const int wk = (wave >> 1) * 32;
    const int wd = (wave & 1) * 32;

    floatx4 acc[2][2] = {};
    float c1[4] = {}, c2[4] = {};
    const int k4s = (t & 15) * 4;       // this thread's d-range (same for both l)

    for (int q0 = 0; q0 < NSEQ; q0 += 64) {
        ushort4 a0[2], a1[2], v0[2], v1[2];
        float2 rr[2];
        #pragma unroll
        for (int l = 0; l < 2; l++) {
            int c = t + l * 256;          // 0..511
            int k4 = (c & 15) * 4;
            int qp = c >> 4;
            a0[l] = *(const ushort4*)(Ai + (size_t)(q0 + 2 * qp)     * NSEQ + k0 + k4);
            a1[l] = *(const ushort4*)(Ai + (size_t)(q0 + 2 * qp + 1) * NSEQ + k0 + k4);
            v0[l] = *(const ushort4*)(Vi + (size_t)(q0 + 2 * qp)     * DH + k4);
            v1[l] = *(const ushort4*)(Vi + (size_t)(q0 + 2 * qp + 1) * DH + k4);
            rr[l] = *(const float2*)(Rb + q0 + 2 * qp);
        }
        __syncthreads();
        #pragma unroll
        for (int l = 0; l < 2; l++) {
            int c = t + l * 256;
            int k4 = (c & 15) * 4;
            int qp = c >> 4;
            const unsigned short* pa0 = (const unsigned short*)&a0[l];
            const unsigned short* pa1 = (const unsigned short*)&a1[l];
            const unsigned short* pv0 = (const unsigned short*)&v0[l];
            const unsigned short* pv1 = (const unsigned short*)&v1[l];
            #pragma unroll
            for (int j = 0; j < 4; j++) {
                At[(k4 + j) * 33 + qp] = (u32)pa0[j] | ((u32)pa1[j] << 16);
                float vf0 = bf2f(pv0[j]), vf1 = bf2f(pv1[j]);
                float s0 = rr[l].x * vf0, s1 = rr[l].y * vf1;
                u32 w;
                __bf16* wb = (__bf16*)&w;
                wb[0] = (__bf16)s0;       // compiler: v_cvt_pk_bf16_f32
                wb[1] = (__bf16)s1;
                Vt[(k4 + j) * 33 + qp] = w;
                c1[j] += s0 + s1;
                c2[j] += vf0 + vf1;
            }
        }
        __syncthreads();

        #pragma unroll
        for (int ks = 0; ks < 2; ks++) {
            const int qo = ks * 16 + g * 4;
            bf16x8 af[2], bf[2];
            #pragma unroll
            for (int mt = 0; mt < 2; mt++) {
                const u32* r = &At[(wk + mt * 16 + m) * 33 + qo];
                uint4 w; w.x = r[0]; w.y = r[1]; w.z = r[2]; w.w = r[3];
                af[mt] = *(bf16x8*)&w;
            }
            #pragma unroll
            for (int nt = 0; nt < 2; nt++) {
                const u32* r = &Vt[(wd + nt * 16 + m) * 33 + qo];
                uint4 w; w.x = r[0]; w.y = r[1]; w.z = r[2]; w.w = r[3];
                bf[nt] = *(bf16x8*)&w;
            }
            #pragma unroll
            for (int mt = 0; mt < 2; mt++)
                #pragma unroll
                for (int nt = 0; nt < 2; nt++)
                    acc[mt][nt] = __builtin_amdgcn_mfma_f32_16x16x32_bf16(
                        af[mt], bf[nt], acc[mt][nt], 0, 0, 0);
        }
    }

    // ---- reduce C1/C2 across the 16 qp-groups (reuse At/Vt as float arrays)
    __syncthreads();
    float* c1l = (float*)At;              // [16][64] partials + [64] final at 1024
    float* c2l = (float*)Vt;
    const int grp = t >> 4;
    #pragma unroll
    for (int j = 0; j < 4; j++) {
        c1l[grp * 64 + k4s + j] = c1[j];
        c2l[grp * 64 + k4s + j] = c2[j];
    }
    __syncthreads();
    if (t < 64) {
        float s1_ = 0.f, s2_ = 0.f;
        #pragma unroll
        for (int g2 = 0; g2 < 16; g2++) {
            s1_ += c1l[g2 * 64 + t];
            s2_ += c2l[g2 * 64 + t];
        }
        c1l[1024 + t] = s1_;
        c2l[1024 + t] = s2_;
    }
    __syncthreads();

    float mean = 0.f;
    #pragma unroll
    for (int h = 0; h < 12; h++) mean += theta[h * 12 + i];
    mean *= (1.0f / 1024.0f);

    #pragma unroll
    for (int mt = 0; mt < 2; mt++) {
        int kb = k0 + wk + mt * 16 + g * 4;
        float4 ls4 = *(const float4*)(ln_scale + kb);
        float4 lb4 = *(const float4*)(ln_bias + kb);
        #pragma unroll
        for (int nt = 0; nt < 2; nt++) {
            int d = wd + nt * 16 + m;
            float C1d = c1l[1024 + d], C2d = c2l[1024 + d];
            #pragma unroll
            for (int r = 0; r < 4; r++) {
                float lns = (&ls4.x)[r], lnb = (&lb4.x)[r];
                float val = lns * (acc[mt][nt][r] - mean * C1d) + lnb * C2d;
                out[((size_t)(b * NSEQ + kb + r)) * DMODEL + i * DH + d] = val;
            }
        }
    }
}

extern "C" void kernel_launch(void* const* d_in, const int* in_sizes, int n_in,
                              void* d_out, int out_size, void* d_ws, size_t ws_size,
                              hipStream_t stream) {
    const float* x     = (const float*)d_in[0];
    const float* Wq    = (const float*)d_in[1];
    const float* Wk    = (const float*)d_in[2];
    const float* Wv    = (const float*)d_in[3];
    const float* theta = (const float*)d_in[4];
    const float* ln_s  = (const float*)d_in[5];
    const float* ln_b  = (const float*)d_in[6];
    float* out = (float*)d_out;

    char* ws = (char*)d_ws;
    const size_t qsz = (size_t)NB * NSEQ * DMODEL * sizeof(unsigned short); // 6.29 MB
    unsigned short* Q = (unsigned short*)(ws);
    unsigned short* K = (unsigned short*)(ws + qsz);
    unsigned short* V = (unsigned short*)(ws + 2 * qsz);
    unsigned short* P = (unsigned short*)(ws + 3 * qsz);  // 100.7 MB, becomes T in-place
    unsigned short* xb = P;
    unsigned short* Wt = P + (size_t)NB * NSEQ * DMODEL;  // 3 x 768 x 768 bf16

    float* Lpart = out;                      // [48 * 8 * 1024 floats]
    float* Rbuf  = (float*)K;                // [48 * 1024 floats] (K dead after score)

    prep<<<dim3(1536 + 432), 256, 0, stream>>>(x, xb, Wq, Wk, Wv, Wt);
    qkv_mfma<<<dim3(NB * NSEQ / 128, DMODEL / 128, 3), 256, 0, stream>>>(
        xb, Wt, Q, K, V);
    score_gemm<<<dim3(NSEQ / 128, NSEQ / 128, NB * NH), 256, 0, stream>>>(Q, K, P, Lpart);
    mix_t<<<dim3(NSEQ, NB), 256, 0, stream>>>(P, theta, Lpart, Rbuf);
    av_mfma<<<dim3(NSEQ / 64, NH, NB), 256, 0, stream>>>(
        P, V, Rbuf, theta, ln_s, ln_b, out);
}